// Round 11
// baseline (76.809 us; speedup 1.0000x reference)
//
#include <hip/hip_runtime.h>

// Fused, reads p once, writes out once. Per (b, 4-row strip):
//  phase 1: 16 chunks of 8 channels through a DOUBLE-BUFFERED XOR-swizzled slab
//           (1 barrier/chunk, 3-deep reg prefetch); accumulate 9 sums
//           S_d = sum_c p[x]*p[x+d]; retain center quads in keep[16].
//  phase 2: inv = 1/sqrt(S_center) (+halo), sim = (1/9)*inv*sum_d inv[x+d]*S_d,
//           computed in BOTH chalf lanes.
//  phase 3: NO LDS — adjacent chalf lanes swap 2 floats via __shfl_xor(,1) (DPP);
//           each lane stores 16 float4 covering a dense 256B span (L2 merges).
// amdgpu_waves_per_eu(3,4): VGPR budget >=168 so keep[16] is NOT spilled
// (round-10 counter-proof: unhinted allocator squeezed to 64 VGPR and spilled
//  ~26 MB to scratch; WRITE_SIZE 160 MB vs 134 ideal).

__device__ __forceinline__ float dot4acc(float4 a, float4 b, float acc) {
    acc = fmaf(a.x, b.x, acc);
    acc = fmaf(a.y, b.y, acc);
    acc = fmaf(a.z, b.z, acc);
    acc = fmaf(a.w, b.w, acc);
    return acc;
}

__global__ __attribute__((amdgpu_waves_per_eu(3, 4))) __launch_bounds__(256)
void bcim_fused(const float* __restrict__ p, float* __restrict__ out) {
    __shared__ float slab[2 * 1536];   // two halves: [6 rows][64 quads][4]
    __shared__ float invL[192];

    const int tid = threadIdx.x;
    const int b  = blockIdx.x >> 3;
    const int r0 = (blockIdx.x & 7) << 2;
    const float* __restrict__ pb = p + (size_t)b * 131072;

    // ---- loader mapping (v3-verified) ----
    const int l_wq = tid & 7;
    const int l_c  = (tid >> 3) & 7;
    const int l_r  = tid >> 6;
    const int g0r  = r0 - 1 + l_r;
    const int g1r  = r0 + 3 + l_r;
    const bool in0 = ((unsigned)g0r < 32u);
    const bool in1 = (tid < 128) && ((unsigned)g1r < 32u);
    int wOff[4];
    {
        const int chh = l_c >> 2;
        const int ci  = l_c & 3;
        #pragma unroll
        for (int j = 0; j < 4; ++j) {
            const int u = ((l_wq << 3) + (j << 1) + chh) ^ l_wq;
            wOff[j] = l_r * 256 + u * 4 + ci;
        }
    }
    const int gOff0 = l_c * 1024 + g0r * 32 + l_wq * 4;
    const int gOff1 = l_c * 1024 + g1r * 32 + l_wq * 4;

    // ---- stencil mapping (v3-verified) ----
    const int chalf = tid & 1;
    const int pos   = tid >> 1;
    const int h     = pos >> 5;
    const int w     = pos & 31;
    const int wm    = (w > 0) ? w - 1 : 0;
    const int wp    = (w < 31) ? w + 1 : 31;
    const int uc    = (w  * 2 + chalf) ^ (w  >> 2);
    const int um    = (wm * 2 + chalf) ^ (wm >> 2);
    const int up    = (wp * 2 + chalf) ^ (wp >> 2);

    const float4 z4 = make_float4(0.f, 0.f, 0.f, 0.f);
    float4 Ca = z4, Cb = z4, S0a = z4, S0b = z4, S1a = z4, S1b = z4;
    if (in0) Ca  = *(const float4*)(pb + gOff0);            // chunk 0
    if (in1) Cb  = *(const float4*)(pb + gOff1);
    if (in0) S0a = *(const float4*)(pb + 8192 + gOff0);     // chunk 1
    if (in1) S0b = *(const float4*)(pb + 8192 + gOff1);
    if (in0) S1a = *(const float4*)(pb + 16384 + gOff0);    // chunk 2
    if (in1) S1b = *(const float4*)(pb + 16384 + gOff1);

    float s0=0.f,s1=0.f,s2=0.f,s3=0.f,s4=0.f,s5=0.f,s6=0.f,s7=0.f,s8=0.f,hn=0.f;
    float4 keep[16];

    #define WR(OFF, Ra, Rb) {                                                       \
        slab[(OFF) + wOff[0]] = Ra.x; slab[(OFF) + wOff[1]] = Ra.y;                 \
        slab[(OFF) + wOff[2]] = Ra.z; slab[(OFF) + wOff[3]] = Ra.w;                 \
        if (tid < 128) {                                                            \
            slab[(OFF) + wOff[0] + 1024] = Rb.x; slab[(OFF) + wOff[1] + 1024] = Rb.y; \
            slab[(OFF) + wOff[2] + 1024] = Rb.z; slab[(OFF) + wOff[3] + 1024] = Rb.w; \
        } }

    WR(0, Ca, Cb)           // chunk 0 -> half 0
    __syncthreads();

    #pragma unroll
    for (int k = 0; k < 16; ++k) {
        // write chunk k+1 into the other half; reload its reg set with chunk k+3
        if (k < 15) {
            const int woff = ((k + 1) & 1) * 1536;
            if ((k & 1) == 0) {
                WR(woff, S0a, S0b)
                if (k + 3 < 16) {
                    if (in0) S0a = *(const float4*)(pb + (k + 3) * 8192 + gOff0);
                    if (in1) S0b = *(const float4*)(pb + (k + 3) * 8192 + gOff1);
                }
            } else {
                WR(woff, S1a, S1b)
                if (k + 3 < 16) {
                    if (in0) S1a = *(const float4*)(pb + (k + 3) * 8192 + gOff0);
                    if (in1) S1b = *(const float4*)(pb + (k + 3) * 8192 + gOff1);
                }
            }
        }
        // compute chunk k from half (k&1)
        {
            const float4* sp = (const float4*)&slab[(k & 1) * 1536];
            const float4 ctr = sp[(h + 1) * 64 + uc];
            keep[k] = ctr;
            float4 n0 = sp[h * 64 + um];
            float4 n1 = sp[h * 64 + uc];
            float4 n2 = sp[h * 64 + up];
            s0 = dot4acc(ctr, n0, s0);
            s1 = dot4acc(ctr, n1, s1);
            s2 = dot4acc(ctr, n2, s2);
            if (h == 0) hn = dot4acc(n1, n1, hn);
            n0 = sp[(h + 2) * 64 + um];
            n1 = sp[(h + 2) * 64 + uc];
            n2 = sp[(h + 2) * 64 + up];
            s6 = dot4acc(ctr, n0, s6);
            s7 = dot4acc(ctr, n1, s7);
            s8 = dot4acc(ctr, n2, s8);
            if (h == 3) hn = dot4acc(n1, n1, hn);
            n0 = sp[(h + 1) * 64 + um];
            n2 = sp[(h + 1) * 64 + up];
            s3 = dot4acc(ctr, n0, s3);
            s4 = dot4acc(ctr, ctr, s4);
            s5 = dot4acc(ctr, n2, s5);
        }
        __syncthreads();
    }
    #undef WR

    // pair-reduce channel halves (lanes 2k <-> 2k+1): both lanes get full sums
    s0 += __shfl_xor(s0, 1); s1 += __shfl_xor(s1, 1); s2 += __shfl_xor(s2, 1);
    s3 += __shfl_xor(s3, 1); s4 += __shfl_xor(s4, 1); s5 += __shfl_xor(s5, 1);
    s6 += __shfl_xor(s6, 1); s7 += __shfl_xor(s7, 1); s8 += __shfl_xor(s8, 1);
    hn += __shfl_xor(hn, 1);

    if (chalf == 0) {
        invL[(h + 1) * 32 + w] = (s4 > 0.f) ? (1.0f / sqrtf(s4)) : 0.f;
        if (h == 0) invL[w]       = (hn > 0.f) ? (1.0f / sqrtf(hn)) : 0.f;
        if (h == 3) invL[160 + w] = (hn > 0.f) ? (1.0f / sqrtf(hn)) : 0.f;
    }
    __syncthreads();

    float simreg;
    {
        const float mL = (w > 0)  ? 1.f : 0.f;
        const float mR = (w < 31) ? 1.f : 0.f;
        const float* iT = invL + h * 32;
        const float* iM = iT + 32;
        const float* iB = iM + 32;
        float acc;
        acc = s0 * (iT[wm] * mL);
        acc = fmaf(s1, iT[w],       acc);
        acc = fmaf(s2, iT[wp] * mR, acc);
        acc = fmaf(s3, iM[wm] * mL, acc);
        acc = fmaf(s4, iM[w],       acc);
        acc = fmaf(s5, iM[wp] * mR, acc);
        acc = fmaf(s6, iB[wm] * mL, acc);
        acc = fmaf(s7, iB[w],       acc);
        acc = fmaf(s8, iB[wp] * mR, acc);
        simreg = acc * iM[w] * (1.0f / 9.0f);
    }

    // ---- phase 3: register->global via lane-pair DPP exchange (no LDS) ----
    // lane (pos, chalf) holds keep[ch] = p[ch*8 + chalf*4 + (0..3), pos].
    // output quad (t=chalf, q=ch*4..ch*4+3): needs {e_t, e_{t+2}} from BOTH lanes.
    float* op = out + (size_t)b * 131072 + (size_t)chalf * 65536 +
                (size_t)(r0 + h) * 2048 + (size_t)w * 64;
    #pragma unroll
    for (int ch = 0; ch < 16; ++ch) {
        float4 kk = keep[ch];
        kk.x *= simreg; kk.y *= simreg; kk.z *= simreg; kk.w *= simreg;
        const float sA = chalf ? kk.x : kk.y;   // send partner's needed e
        const float sB = chalf ? kk.z : kk.w;
        const float eA = __shfl_xor(sA, 1);
        const float eB = __shfl_xor(sB, 1);
        float4 o;
        if (chalf == 0) { o.x = kk.x; o.y = kk.z; o.z = eA;   o.w = eB;   }
        else            { o.x = eA;   o.y = eB;   o.z = kk.y; o.w = kk.w; }
        *(float4*)(op + ch * 4) = o;
    }
}

extern "C" void kernel_launch(void* const* d_in, const int* in_sizes, int n_in,
                              void* d_out, int out_size, void* d_ws, size_t ws_size,
                              hipStream_t stream) {
    const float* p = (const float*)d_in[0];
    float* out = (float*)d_out;
    bcim_fused<<<dim3(2048), dim3(256), 0, stream>>>(p, out);
    (void)in_sizes; (void)n_in; (void)out_size; (void)d_ws; (void)ws_size;
}